// Round 23
// baseline (111.134 us; speedup 1.0000x reference)
//
#include <hip/hip_runtime.h>
#include <math.h>

#define SIG_L 128000
#define NBATCH 64
#define NROWS 257
#define HOP 128
#define NUMF 999
#define NFRM 30
#define NWIN 969
#define NB_MAX 16
#define FBINS 160          // kmap entries (>= 144 used bins)
#define TILES 9            // M = 288 rows = 144 bins x (re,im)
#define KSTEPS 16
#define FPBX 256           // frames per task (four 64-columns)
#define AKB 18432          // bytes per A kk-chunk (9 tiles x 2 planes x 1024B)
#define BCH 4112           // B 16-byte chunks: (255*128+256)/8 = 4112
#define SMEMSZ (2 * AKB + BCH * 16 + NB_MAX * FPBX * 4 + 640)
#define BETA_F 6.623413251903491f  // 1 + 10^(15/20)

typedef __attribute__((ext_vector_type(8))) short short8;
typedef __attribute__((ext_vector_type(16))) float f32x16;
typedef unsigned short ushort_t;

// RNE split of fp32 into bf16 hi + bf16 lo (hi RNE; rem = v - hi exact in fp32)
__device__ inline ushort_t bf_hi_rne(float v, float* rem) {
    unsigned u = __float_as_uint(v);
    unsigned hr = (u + 0x7FFFu + ((u >> 16) & 1u)) & 0xFFFF0000u;
    *rem = v - __uint_as_float(hr);
    return (ushort_t)(hr >> 16);
}
__device__ inline ushort_t bf_rne(float v) {
    unsigned u = __float_as_uint(v);
    return (ushort_t)((u + 0x7FFFu + ((u >> 16) & 1u)) >> 16);
}

__device__ inline void gll16(const void* g, void* l) {
    __builtin_amdgcn_global_load_lds(
        (const __attribute__((address_space(1))) unsigned int*)g,
        (__attribute__((address_space(3))) unsigned int*)l, 16, 0, 0);
}

// ---------- K0: merged setup. block 0: octmat scan. blocks 1..288: weight pack ----------
__global__ void k_setup(const float* __restrict__ oct, const float* __restrict__ fftmat,
                        int NB, int* __restrict__ hdr, ushort_t* __restrict__ wpack) {
    const int tid = threadIdx.x;
    if (blockIdx.x == 0) {
        __shared__ int smin[16], smax[16];
        if (tid < NB) { smin[tid] = 0x7fffffff; smax[tid] = -1; }
        __syncthreads();
        for (int idx = tid; idx < NB * NROWS; idx += blockDim.x) {
            int k = idx / NROWS, f = idx % NROWS;
            if (oct[idx] != 0.0f) { atomicMin(&smin[k], f); atomicMax(&smax[k], f); }
        }
        __syncthreads();
        if (tid < FBINS) {
            int kid = -1;
            for (int k = 0; k < NB; ++k)
                if (smax[k] >= 0 && tid >= smin[k] && tid <= smax[k]) kid = k;
            hdr[32 + tid] = kid;
        }
        return;
    }
    const int bx = blockIdx.x - 1;      // 0..287
    for (int u = 0; u < 2; ++u) {
        int idx = bx * 512 + u * 256 + tid;     // < 147456
        int e = idx & 7, l = (idx >> 3) & 63, p = (idx >> 9) & 1;
        int tt = (idx >> 10) % TILES, kk = (idx >> 10) / TILES;
        int row32 = l & 31, kq = l >> 5;
        int bin = tt * 16 + (row32 >> 1);
        int part = row32 & 1;
        int k = kk * 16 + kq * 8 + e;
        float v = fftmat[(size_t)(part ? (NROWS + bin) : bin) * 512 + 128 + k];
        float rem; ushort_t hb = bf_hi_rne(v, &rem);
        wpack[idx] = p ? bf_rne(rem) : hb;
    }
}

// ---------- K1: persistent MFMA STFT (2 tasks/block) — r19 configuration ----------
__global__ __launch_bounds__(768, 3) void k_stft(
    const float* __restrict__ targ, const float* __restrict__ pred,
    const ushort_t* __restrict__ wpack, const int* __restrict__ hdr,
    float* __restrict__ xbuf, float* __restrict__ ybuf, int NB) {
    __shared__ __align__(16) char smem[SMEMSZ];
    ushort_t* As    = (ushort_t*)smem;
    char*     Bs    = smem + 2 * AKB;
    float*    bacc  = (float*)(smem + 2 * AKB + BCH * 16);
    int*      kmapS = (int*)(smem + 2 * AKB + BCH * 16 + NB_MAX * FPBX * 4);

    const int tid = threadIdx.x;
    const int lane = tid & 63;
    const int wv = __builtin_amdgcn_readfirstlane(tid >> 6); // 0..11
    const int mg  = wv >> 2;
    const int col = wv & 3;
    const int tbase = mg * 3;
    const int jloc = lane & 31, kq = lane >> 5;

    for (int i = tid; i < FBINS; i += 768) kmapS[i] = hdr[32 + i];

#pragma unroll 1
    for (int task = 0; task < 2; ++task) {
        const int t = (int)blockIdx.x + 256 * task;
        const int z = t & 1, b = (t >> 1) & 63, tile = (t >> 7) & 3;
        const int t0 = tile * FPBX;
        const float* __restrict__ sig = z ? pred : targ;
        float* __restrict__ out = z ? ybuf : xbuf;
        const size_t boff = (size_t)b * SIG_L;

        if (task) __syncthreads();
        for (int i = tid; i < NB_MAX * FPBX; i += 768) bacc[i] = 0.0f;

        // ---- B stage: 12 loads issued up-front (branchless), then cvt+swz writes
        const long sbase = (long)t0 * HOP;
        float4 xr[12];
#pragma unroll
        for (int u = 0; u < 6; ++u) {
            const int c = tid + u * 768;
            const long g0 = sbase + (long)c * 8;
            const bool full = (c < BCH) && (g0 + 8 <= SIG_L);
            const long gc = full ? g0 : 0;
            const float* p = sig + boff + gc;
            float4 a0 = *(const float4*)(p);
            float4 a1 = *(const float4*)(p + 4);
            if (!full) { a0 = (float4){0,0,0,0}; a1 = (float4){0,0,0,0}; }
            xr[2*u] = a0; xr[2*u+1] = a1;
        }
#pragma unroll
        for (int u = 0; u < 6; ++u) {
            const int c = tid + u * 768;
            if (c < BCH) {
                short8 sv;
                sv[0]=(short)bf_rne(xr[2*u].x);   sv[1]=(short)bf_rne(xr[2*u].y);
                sv[2]=(short)bf_rne(xr[2*u].z);   sv[3]=(short)bf_rne(xr[2*u].w);
                sv[4]=(short)bf_rne(xr[2*u+1].x); sv[5]=(short)bf_rne(xr[2*u+1].y);
                sv[6]=(short)bf_rne(xr[2*u+1].z); sv[7]=(short)bf_rne(xr[2*u+1].w);
                int byte = c * 16;
                byte ^= ((byte >> 8) & 0xF) << 4;
                *(short8*)(Bs + byte) = sv;
            }
        }
        // ---- A stage kk=0 into As[0] ----
        {
            const char* gsrc = (const char*)wpack;
            for (int j = wv; j < 18; j += 12)
                gll16(gsrc + j * 1024 + lane * 16, smem + j * 1024);
        }
        __syncthreads();

        f32x16 acc[3][2];
#pragma unroll
        for (int g = 0; g < 3; ++g)
#pragma unroll
            for (int bt = 0; bt < 2; ++bt)
#pragma unroll
                for (int e = 0; e < 16; ++e) acc[g][bt][e] = 0.0f;

        int cur = 0;
#pragma unroll 1
        for (int kk = 0; kk < KSTEPS; ++kk) {
            if (kk < KSTEPS - 1) {
                const char* gsrc = (const char*)wpack + (size_t)(kk + 1) * AKB;
                char* ldst = smem + (cur ^ 1) * AKB;
                for (int j = wv; j < 18; j += 12)
                    gll16(gsrc + j * 1024 + lane * 16, ldst + j * 1024);
            }
            short8 S[2];
#pragma unroll
            for (int bt = 0; bt < 2; ++bt) {
                const int fl = col * 64 + bt * 32 + jloc;
                int byte = fl * 256 + kk * 32 + kq * 16;
                byte ^= ((byte >> 8) & 0xF) << 4;
                S[bt] = *(const short8*)(Bs + byte);
            }
            const ushort_t* ab = As + cur * (AKB / 2) + tbase * 1024 + lane * 8;
            short8 Ah[3], Al[3];
#pragma unroll
            for (int g = 0; g < 3; ++g) {
                Ah[g] = *(const short8*)(ab + g * 1024);
                Al[g] = *(const short8*)(ab + g * 1024 + 512);
            }
#pragma unroll
            for (int g = 0; g < 3; ++g)
                acc[g][0] = __builtin_amdgcn_mfma_f32_32x32x16_bf16(Ah[g], S[0], acc[g][0], 0, 0, 0);
#pragma unroll
            for (int g = 0; g < 3; ++g)
                acc[g][1] = __builtin_amdgcn_mfma_f32_32x32x16_bf16(Ah[g], S[1], acc[g][1], 0, 0, 0);
#pragma unroll
            for (int g = 0; g < 3; ++g)
                acc[g][0] = __builtin_amdgcn_mfma_f32_32x32x16_bf16(Al[g], S[0], acc[g][0], 0, 0, 0);
#pragma unroll
            for (int g = 0; g < 3; ++g)
                acc[g][1] = __builtin_amdgcn_mfma_f32_32x32x16_bf16(Al[g], S[1], acc[g][1], 0, 0, 0);
            __syncthreads();
            cur ^= 1;
        }

        // ---- epilogue: energies -> band accumulate -> global ----
#pragma unroll
        for (int g = 0; g < 3; ++g) {
#pragma unroll
            for (int bt = 0; bt < 2; ++bt) {
                const int fl = col * 64 + bt * 32 + jloc;
                float run = 0.0f; int runk = -1;
#pragma unroll
                for (int rr = 0; rr < 8; ++rr) {
                    const int m = (rr & 1) + 4 * (rr >> 1) + 2 * kq;
                    const int kid = kmapS[(tbase + g) * 16 + m];
                    const float vr = acc[g][bt][rr * 2], vi = acc[g][bt][rr * 2 + 1];
                    const float e = vr * vr + vi * vi;
                    if (kid != runk) {
                        if (runk >= 0) atomicAdd(&bacc[runk * FPBX + fl], run);
                        run = 0.0f; runk = kid;
                    }
                    if (kid >= 0) run += e;
                }
                if (runk >= 0) atomicAdd(&bacc[runk * FPBX + fl], run);
            }
        }
        __syncthreads();
        for (int idx = tid; idx < NB * FPBX; idx += 768) {
            int k = idx >> 8, tt = idx & (FPBX - 1);
            int tg = t0 + tt;
            if (tg < NUMF)
                out[((size_t)b * NB + k) * NUMF + tg] = bacc[k * FPBX + tt];
        }
    }
}

// ---------- K2: sliding-window correlations, register-windowed, direct-global ----------
// xbuf/ybuf rows are L2-hot (just produced); neighboring threads read
// overlapping 33-element spans -> L1/L2 serve them. No LDS staging, no barrier.
__global__ __launch_bounds__(256) void k_corr(const float* __restrict__ xbuf,
                                              const float* __restrict__ ybuf,
                                              int NB, double* __restrict__ partials) {
    const int k = blockIdx.x, b = blockIdx.y;
    const long roff = ((long)b * NB + k) * NUMF;
    __shared__ double red[256];
    const int tid = threadIdx.x;

    const int w0 = tid * 4;                 // windows w0..w0+3
    float xr[33], yr[33];
#pragma unroll
    for (int i = 0; i < 33; ++i) {
        int idx = w0 + i; idx = (idx < NUMF) ? idx : (NUMF - 1);
        xr[i] = sqrtf(xbuf[roff + idx]);
        yr[i] = sqrtf(ybuf[roff + idx]);
    }
    double loc = 0.0;
#pragma unroll
    for (int j = 0; j < 4; ++j) {
        const int w = w0 + j;
        if (w < NWIN) {
            float sx = 0, sxx = 0, syy = 0;
#pragma unroll
            for (int i = 0; i < NFRM; ++i) {
                float xv = xr[j + i], yv = yr[j + i];
                sx += xv; sxx += xv * xv; syy += yv * yv;
            }
            float alpha = sqrtf(sxx / (syy + 1e-7f));
            float sy = 0;
#pragma unroll
            for (int i = 0; i < NFRM; ++i)
                sy += fminf(alpha * yr[j + i], BETA_F * xr[j + i]);
            float mx = sx * (1.0f / NFRM), my = sy * (1.0f / NFRM);
            float cxx = 0, cyy = 0, cxy = 0;
#pragma unroll
            for (int i = 0; i < NFRM; ++i) {
                float dx = xr[j + i] - mx;
                float dy = fminf(alpha * yr[j + i], BETA_F * xr[j + i]) - my;
                cxx += dx * dx; cyy += dy * dy; cxy += dx * dy;
            }
            loc += (double)cxy / sqrt((double)cxx * (double)cyy);
        }
    }
    red[tid] = loc;
    __syncthreads();
    for (int s = 128; s > 0; s >>= 1) {
        if (tid < s) red[tid] += red[tid + s];
        __syncthreads();
    }
    if (tid == 0) partials[b * NB + k] = red[0];
}

// ---------- K3: final deterministic reduction ----------
__global__ void k_final(const double* __restrict__ partials, int NB, float* __restrict__ out) {
    __shared__ double red[256];
    const int tid = threadIdx.x;
    const int n = NBATCH * NB;
    double s = 0.0;
    for (int i = tid; i < n; i += 256) s += partials[i];
    red[tid] = s;
    __syncthreads();
    for (int st = 128; st > 0; st >>= 1) {
        if (tid < st) red[tid] += red[tid + st];
        __syncthreads();
    }
    if (tid == 0) out[0] = (float)(-red[0] / ((double)NBATCH * NB * NWIN));
}

extern "C" void kernel_launch(void* const* d_in, const int* in_sizes, int n_in,
                              void* d_out, int out_size, void* d_ws, size_t ws_size,
                              hipStream_t stream) {
    const float* pred   = (const float*)d_in[0];
    const float* targ   = (const float*)d_in[1];
    const float* fftmat = (const float*)d_in[3];
    const float* oct    = (const float*)d_in[4];
    const int NB = in_sizes[4] / NROWS;   // 15

    char* ws = (char*)d_ws;
    int*      hdr   = (int*)ws;                          // 1 KB
    ushort_t* wpack = (ushort_t*)(ws + 1024);            // 147456 shorts = 294912 B
    size_t o1 = 1024 + (size_t)KSTEPS * TILES * 2 * 512 * 2;
    size_t xsz = (size_t)NBATCH * NB_MAX * NUMF * 4;
    float*  xbuf = (float*)(ws + o1);
    float*  ybuf = (float*)(ws + o1 + xsz);
    double* partials = (double*)(ws + o1 + 2 * xsz);

    hipLaunchKernelGGL(k_setup, dim3(289), dim3(256), 0, stream, oct, fftmat, NB, hdr, wpack);
    hipLaunchKernelGGL(k_stft, dim3(256), dim3(768), 0, stream,
                       targ, pred, wpack, hdr, xbuf, ybuf, NB);
    hipLaunchKernelGGL(k_corr, dim3(NB, NBATCH), dim3(256), 0, stream, xbuf, ybuf, NB, partials);
    hipLaunchKernelGGL(k_final, dim3(1), dim3(256), 0, stream, partials, NB, (float*)d_out);
}

// Round 24
// 99.235 us; speedup vs baseline: 1.1199x; 1.1199x over previous
//
#include <hip/hip_runtime.h>
#include <math.h>

#define SIG_L 128000
#define NBATCH 64
#define NROWS 257
#define HOP 128
#define NUMF 999
#define NFRM 30
#define NWIN 969
#define NB_MAX 16
#define FBINS 160          // kmap entries (>= 144 used bins)
#define TILES 9            // M = 288 rows = 144 bins x (re,im)
#define KSTEPS 16
#define FPBX 256           // frames per task (four 64-columns)
#define AKB 18432          // bytes per A kk-chunk (9 tiles x 2 planes x 1024B)
#define BCH 4112           // B 16-byte chunks: (255*128+256)/8 = 4112
#define SMEMSZ (2 * AKB + BCH * 16 + NB_MAX * FPBX * 4 + 640)
#define BETA_F 6.623413251903491f  // 1 + 10^(15/20)

typedef __attribute__((ext_vector_type(8))) short short8;
typedef __attribute__((ext_vector_type(16))) float f32x16;
typedef unsigned short ushort_t;

// RNE split of fp32 into bf16 hi + bf16 lo (hi RNE; rem = v - hi exact in fp32)
__device__ inline ushort_t bf_hi_rne(float v, float* rem) {
    unsigned u = __float_as_uint(v);
    unsigned hr = (u + 0x7FFFu + ((u >> 16) & 1u)) & 0xFFFF0000u;
    *rem = v - __uint_as_float(hr);
    return (ushort_t)(hr >> 16);
}
__device__ inline ushort_t bf_rne(float v) {
    unsigned u = __float_as_uint(v);
    return (ushort_t)((u + 0x7FFFu + ((u >> 16) & 1u)) >> 16);
}

__device__ inline void gll16(const void* g, void* l) {
    __builtin_amdgcn_global_load_lds(
        (const __attribute__((address_space(1))) unsigned int*)g,
        (__attribute__((address_space(3))) unsigned int*)l, 16, 0, 0);
}

// ---------- K0: merged setup. block 0: octmat scan. blocks 1..288: weight pack ----------
__global__ void k_setup(const float* __restrict__ oct, const float* __restrict__ fftmat,
                        int NB, int* __restrict__ hdr, ushort_t* __restrict__ wpack) {
    const int tid = threadIdx.x;
    if (blockIdx.x == 0) {
        __shared__ int smin[16], smax[16];
        if (tid < NB) { smin[tid] = 0x7fffffff; smax[tid] = -1; }
        __syncthreads();
        for (int idx = tid; idx < NB * NROWS; idx += blockDim.x) {
            int k = idx / NROWS, f = idx % NROWS;
            if (oct[idx] != 0.0f) { atomicMin(&smin[k], f); atomicMax(&smax[k], f); }
        }
        __syncthreads();
        if (tid < FBINS) {
            int kid = -1;
            for (int k = 0; k < NB; ++k)
                if (smax[k] >= 0 && tid >= smin[k] && tid <= smax[k]) kid = k;
            hdr[32 + tid] = kid;
        }
        return;
    }
    const int bx = blockIdx.x - 1;      // 0..287
    for (int u = 0; u < 2; ++u) {
        int idx = bx * 512 + u * 256 + tid;     // < 147456
        int e = idx & 7, l = (idx >> 3) & 63, p = (idx >> 9) & 1;
        int tt = (idx >> 10) % TILES, kk = (idx >> 10) / TILES;
        int row32 = l & 31, kq = l >> 5;
        int bin = tt * 16 + (row32 >> 1);
        int part = row32 & 1;
        int k = kk * 16 + kq * 8 + e;
        float v = fftmat[(size_t)(part ? (NROWS + bin) : bin) * 512 + 128 + k];
        float rem; ushort_t hb = bf_hi_rne(v, &rem);
        wpack[idx] = p ? bf_rne(rem) : hb;
    }
}

// ---------- K1: persistent MFMA STFT (2 tasks/block) — best-measured configuration ----------
__global__ __launch_bounds__(768, 3) void k_stft(
    const float* __restrict__ targ, const float* __restrict__ pred,
    const ushort_t* __restrict__ wpack, const int* __restrict__ hdr,
    float* __restrict__ xbuf, float* __restrict__ ybuf, int NB) {
    __shared__ __align__(16) char smem[SMEMSZ];
    ushort_t* As    = (ushort_t*)smem;
    char*     Bs    = smem + 2 * AKB;
    float*    bacc  = (float*)(smem + 2 * AKB + BCH * 16);
    int*      kmapS = (int*)(smem + 2 * AKB + BCH * 16 + NB_MAX * FPBX * 4);

    const int tid = threadIdx.x;
    const int lane = tid & 63;
    const int wv = __builtin_amdgcn_readfirstlane(tid >> 6); // 0..11
    const int mg  = wv >> 2;
    const int col = wv & 3;
    const int tbase = mg * 3;
    const int jloc = lane & 31, kq = lane >> 5;

    for (int i = tid; i < FBINS; i += 768) kmapS[i] = hdr[32 + i];

#pragma unroll 1
    for (int task = 0; task < 2; ++task) {
        const int t = (int)blockIdx.x + 256 * task;
        const int z = t & 1, b = (t >> 1) & 63, tile = (t >> 7) & 3;
        const int t0 = tile * FPBX;
        const float* __restrict__ sig = z ? pred : targ;
        float* __restrict__ out = z ? ybuf : xbuf;
        const size_t boff = (size_t)b * SIG_L;

        if (task) __syncthreads();
        for (int i = tid; i < NB_MAX * FPBX; i += 768) bacc[i] = 0.0f;

        // ---- B stage: 12 loads issued up-front (branchless), then cvt+swz writes
        const long sbase = (long)t0 * HOP;
        float4 xr[12];
#pragma unroll
        for (int u = 0; u < 6; ++u) {
            const int c = tid + u * 768;
            const long g0 = sbase + (long)c * 8;
            const bool full = (c < BCH) && (g0 + 8 <= SIG_L);
            const long gc = full ? g0 : 0;
            const float* p = sig + boff + gc;
            float4 a0 = *(const float4*)(p);
            float4 a1 = *(const float4*)(p + 4);
            if (!full) { a0 = (float4){0,0,0,0}; a1 = (float4){0,0,0,0}; }
            xr[2*u] = a0; xr[2*u+1] = a1;
        }
#pragma unroll
        for (int u = 0; u < 6; ++u) {
            const int c = tid + u * 768;
            if (c < BCH) {
                short8 sv;
                sv[0]=(short)bf_rne(xr[2*u].x);   sv[1]=(short)bf_rne(xr[2*u].y);
                sv[2]=(short)bf_rne(xr[2*u].z);   sv[3]=(short)bf_rne(xr[2*u].w);
                sv[4]=(short)bf_rne(xr[2*u+1].x); sv[5]=(short)bf_rne(xr[2*u+1].y);
                sv[6]=(short)bf_rne(xr[2*u+1].z); sv[7]=(short)bf_rne(xr[2*u+1].w);
                int byte = c * 16;
                byte ^= ((byte >> 8) & 0xF) << 4;
                *(short8*)(Bs + byte) = sv;
            }
        }
        // ---- A stage kk=0 into As[0] ----
        {
            const char* gsrc = (const char*)wpack;
            for (int j = wv; j < 18; j += 12)
                gll16(gsrc + j * 1024 + lane * 16, smem + j * 1024);
        }
        __syncthreads();

        f32x16 acc[3][2];
#pragma unroll
        for (int g = 0; g < 3; ++g)
#pragma unroll
            for (int bt = 0; bt < 2; ++bt)
#pragma unroll
                for (int e = 0; e < 16; ++e) acc[g][bt][e] = 0.0f;

        int cur = 0;
#pragma unroll 1
        for (int kk = 0; kk < KSTEPS; ++kk) {
            if (kk < KSTEPS - 1) {
                const char* gsrc = (const char*)wpack + (size_t)(kk + 1) * AKB;
                char* ldst = smem + (cur ^ 1) * AKB;
                for (int j = wv; j < 18; j += 12)
                    gll16(gsrc + j * 1024 + lane * 16, ldst + j * 1024);
            }
            short8 S[2];
#pragma unroll
            for (int bt = 0; bt < 2; ++bt) {
                const int fl = col * 64 + bt * 32 + jloc;
                int byte = fl * 256 + kk * 32 + kq * 16;
                byte ^= ((byte >> 8) & 0xF) << 4;
                S[bt] = *(const short8*)(Bs + byte);
            }
            const ushort_t* ab = As + cur * (AKB / 2) + tbase * 1024 + lane * 8;
            __builtin_amdgcn_s_setprio(1);
#pragma unroll
            for (int g = 0; g < 3; ++g) {
                short8 Ah = *(const short8*)(ab + g * 1024);
                short8 Al = *(const short8*)(ab + g * 1024 + 512);
                acc[g][0] = __builtin_amdgcn_mfma_f32_32x32x16_bf16(Ah, S[0], acc[g][0], 0, 0, 0);
                acc[g][1] = __builtin_amdgcn_mfma_f32_32x32x16_bf16(Ah, S[1], acc[g][1], 0, 0, 0);
                acc[g][0] = __builtin_amdgcn_mfma_f32_32x32x16_bf16(Al, S[0], acc[g][0], 0, 0, 0);
                acc[g][1] = __builtin_amdgcn_mfma_f32_32x32x16_bf16(Al, S[1], acc[g][1], 0, 0, 0);
            }
            __builtin_amdgcn_s_setprio(0);
            __syncthreads();
            cur ^= 1;
        }

        // ---- epilogue: energies -> band accumulate -> global ----
#pragma unroll
        for (int g = 0; g < 3; ++g) {
#pragma unroll
            for (int bt = 0; bt < 2; ++bt) {
                const int fl = col * 64 + bt * 32 + jloc;
                float run = 0.0f; int runk = -1;
#pragma unroll
                for (int rr = 0; rr < 8; ++rr) {
                    const int m = (rr & 1) + 4 * (rr >> 1) + 2 * kq;
                    const int kid = kmapS[(tbase + g) * 16 + m];
                    const float vr = acc[g][bt][rr * 2], vi = acc[g][bt][rr * 2 + 1];
                    const float e = vr * vr + vi * vi;
                    if (kid != runk) {
                        if (runk >= 0) atomicAdd(&bacc[runk * FPBX + fl], run);
                        run = 0.0f; runk = kid;
                    }
                    if (kid >= 0) run += e;
                }
                if (runk >= 0) atomicAdd(&bacc[runk * FPBX + fl], run);
            }
        }
        __syncthreads();
        for (int idx = tid; idx < NB * FPBX; idx += 768) {
            int k = idx >> 8, tt = idx & (FPBX - 1);
            int tg = t0 + tt;
            if (tg < NUMF)
                out[((size_t)b * NB + k) * NUMF + tg] = bacc[k * FPBX + tt];
        }
    }
}

// ---------- K2: sliding-window correlations, register-windowed (LDS-staged) ----------
__global__ __launch_bounds__(256) void k_corr(const float* __restrict__ xbuf,
                                              const float* __restrict__ ybuf,
                                              int NB, double* __restrict__ partials) {
    const int k = blockIdx.x, b = blockIdx.y;
    const long roff = ((long)b * NB + k) * NUMF;
    __shared__ float xl[NUMF], yl[NUMF];
    __shared__ double red[256];
    const int tid = threadIdx.x;
    for (int i = tid; i < NUMF; i += 256) {
        xl[i] = sqrtf(xbuf[roff + i]);
        yl[i] = sqrtf(ybuf[roff + i]);
    }
    __syncthreads();

    const int w0 = tid * 4;                 // windows w0..w0+3
    float xr[33], yr[33];
#pragma unroll
    for (int i = 0; i < 33; ++i) {
        int idx = w0 + i; idx = (idx < NUMF) ? idx : (NUMF - 1);
        xr[i] = xl[idx]; yr[i] = yl[idx];
    }
    double loc = 0.0;
#pragma unroll
    for (int j = 0; j < 4; ++j) {
        const int w = w0 + j;
        if (w < NWIN) {
            float sx = 0, sxx = 0, syy = 0;
#pragma unroll
            for (int i = 0; i < NFRM; ++i) {
                float xv = xr[j + i], yv = yr[j + i];
                sx += xv; sxx += xv * xv; syy += yv * yv;
            }
            float alpha = sqrtf(sxx / (syy + 1e-7f));
            float sy = 0;
#pragma unroll
            for (int i = 0; i < NFRM; ++i)
                sy += fminf(alpha * yr[j + i], BETA_F * xr[j + i]);
            float mx = sx * (1.0f / NFRM), my = sy * (1.0f / NFRM);
            float cxx = 0, cyy = 0, cxy = 0;
#pragma unroll
            for (int i = 0; i < NFRM; ++i) {
                float dx = xr[j + i] - mx;
                float dy = fminf(alpha * yr[j + i], BETA_F * xr[j + i]) - my;
                cxx += dx * dx; cyy += dy * dy; cxy += dx * dy;
            }
            loc += (double)cxy / sqrt((double)cxx * (double)cyy);
        }
    }
    red[tid] = loc;
    __syncthreads();
    for (int s = 128; s > 0; s >>= 1) {
        if (tid < s) red[tid] += red[tid + s];
        __syncthreads();
    }
    if (tid == 0) partials[b * NB + k] = red[0];
}

// ---------- K3: final deterministic reduction ----------
__global__ void k_final(const double* __restrict__ partials, int NB, float* __restrict__ out) {
    __shared__ double red[256];
    const int tid = threadIdx.x;
    const int n = NBATCH * NB;
    double s = 0.0;
    for (int i = tid; i < n; i += 256) s += partials[i];
    red[tid] = s;
    __syncthreads();
    for (int st = 128; st > 0; st >>= 1) {
        if (tid < st) red[tid] += red[tid + st];
        __syncthreads();
    }
    if (tid == 0) out[0] = (float)(-red[0] / ((double)NBATCH * NB * NWIN));
}

extern "C" void kernel_launch(void* const* d_in, const int* in_sizes, int n_in,
                              void* d_out, int out_size, void* d_ws, size_t ws_size,
                              hipStream_t stream) {
    const float* pred   = (const float*)d_in[0];
    const float* targ   = (const float*)d_in[1];
    const float* fftmat = (const float*)d_in[3];
    const float* oct    = (const float*)d_in[4];
    const int NB = in_sizes[4] / NROWS;   // 15

    char* ws = (char*)d_ws;
    int*      hdr   = (int*)ws;                          // 1 KB
    ushort_t* wpack = (ushort_t*)(ws + 1024);            // 147456 shorts = 294912 B
    size_t o1 = 1024 + (size_t)KSTEPS * TILES * 2 * 512 * 2;
    size_t xsz = (size_t)NBATCH * NB_MAX * NUMF * 4;
    float*  xbuf = (float*)(ws + o1);
    float*  ybuf = (float*)(ws + o1 + xsz);
    double* partials = (double*)(ws + o1 + 2 * xsz);

    hipLaunchKernelGGL(k_setup, dim3(289), dim3(256), 0, stream, oct, fftmat, NB, hdr, wpack);
    hipLaunchKernelGGL(k_stft, dim3(256), dim3(768), 0, stream,
                       targ, pred, wpack, hdr, xbuf, ybuf, NB);
    hipLaunchKernelGGL(k_corr, dim3(NB, NBATCH), dim3(256), 0, stream, xbuf, ybuf, NB, partials);
    hipLaunchKernelGGL(k_final, dim3(1), dim3(256), 0, stream, partials, NB, (float*)d_out);
}